// Round 7
// baseline (2644.834 us; speedup 1.0000x reference)
//
#include <hip/hip_runtime.h>

// Problem constants
#define A_N   512
#define T_OBS 8
#define PRED  12

typedef __attribute__((ext_vector_type(8))) short bf16x8;
typedef __attribute__((ext_vector_type(4))) float f32x4;
#define MFMA16(a,b,c) __builtin_amdgcn_mfma_f32_16x16x32_bf16((a),(b),(c),0,0,0)

// workspace offsets (bytes)
#define WP_OFF   0            // 128*8192*2 = 2097152
#define WZ_OFF   2097152      // 512*320*2  = 327680
#define BZ_OFF   2424832      // 512*4
#define MASK_OFF 2426880      // 512*4
#define CUR0_OFF 2428928      // 512*2*4
#define CUR1_OFF 2433024
#define HG0_OFF  2437120      // 512*128*2 = 131072
#define HG1_OFF  2568192
#define CS0_OFF  2699264      // 512*128*4 = 262144
#define CS1_OFF  2961408
#define U0_OFF   3223552      // 512*64*128*2 = 8388608
#define U1_OFF   11612160     // ends 20000768 (~20 MB of ws)

static __device__ __forceinline__ unsigned short f2bf(float x){
    union { float f; unsigned u; } v; v.f = x;
    unsigned r = v.u + 0x7fffu + ((v.u >> 16) & 1u);   // RNE
    return (unsigned short)(r >> 16);
}
static __device__ __forceinline__ unsigned pack2(float a, float b){
    return (unsigned)f2bf(a) | ((unsigned)f2bf(b) << 16);
}
static __device__ __forceinline__ float bf2lo(unsigned v){ return __uint_as_float(v << 16); }
static __device__ __forceinline__ float bf2hi(unsigned v){ return __uint_as_float(v & 0xffff0000u); }
static __device__ __forceinline__ float sigm_f(float x){ return 1.f / (1.f + __expf(-x)); }
static __device__ __forceinline__ float tanh_f(float x){
    float e = __expf(-2.f * fabsf(x));
    float t = (1.f - e) / (1.f + e);
    return copysignf(t, x);
}

// ---------------- prep: weights->bf16, zero state, mask decode ----------------
__global__ __launch_bounds__(256) void prep(
    const float* __restrict__ Wp, const float* __restrict__ Wih,
    const float* __restrict__ Whh, const float* __restrict__ bih,
    const float* __restrict__ bhh, const unsigned char* __restrict__ mraw,
    unsigned short* __restrict__ wp_bf, unsigned short* __restrict__ wz,
    float* __restrict__ bz, int* __restrict__ mski,
    unsigned* __restrict__ hg1, float* __restrict__ cs1)
{
    __shared__ int mflagA, mflagB;
    const int bid = blockIdx.x, tid = threadIdx.x;
    const int i0 = bid * 256 + tid, stride = 512 * 256;
    for (int i = i0; i < 524288; i += stride)
        ((unsigned*)wp_bf)[i] = pack2(Wp[2*i], Wp[2*i + 1]);
    for (int i = i0; i < 81920; i += stride){
        int n = (2*i) / 320, k = (2*i) - n*320;
        float w0 = (k < 192)     ? Wih[n*192 + k]     : Whh[n*128 + k - 192];
        float w1 = (k + 1 < 192) ? Wih[n*192 + k + 1] : Whh[n*128 + k + 1 - 192];
        ((unsigned*)wz)[i] = pack2(w0, w1);
    }
    for (int i = i0; i < 512; i += stride) bz[i] = bih[i] + bhh[i];
    for (int i = i0; i < 32768; i += stride) hg1[i] = 0u;        // h(-1) = 0
    for (int i = i0; i < 65536; i += stride) cs1[i] = 0.f;       // c(-1) = 0
    if (bid == 0){
        if (tid == 0){ mflagA = 0; mflagB = 0; }
        __syncthreads();
        for (int j = tid; j < 512; j += 256){
            unsigned char b = mraw[j];
            if (b && (j & 3))        atomicAdd(&mflagA, 1);
            if (b && ((j & 7) == 4)) atomicAdd(&mflagB, 1);
        }
        __syncthreads();
        for (int j = tid; j < 512; j += 256){
            int v;
            if (mflagA)      v = mraw[j] ? 1 : 0;
            else if (mflagB) v = ((const int*)mraw)[j] ? 1 : 0;
            else             v = ((const long long*)mraw)[j] ? 1 : 0;
            mski[j] = v;
        }
    }
}

// ---------------- step: one dispatch = one timestep ---------------------------
// 64 blocks x 512 threads. Block (rg 0..31, ch 0..1): owns rows rg*16..+16.
// Phases: pos/cells/compact -> gather U(t-1) -> x build -> LSTM (both halves,
// redundant) -> gates/c/h -> U(t) own rows x cells [ch*32,+32) -> head (ch==0).
// All cross-block state double-buffered by parity (rd/wr) => no intra-dispatch
// races; cross-step visibility via HW dispatch-boundary coherence.
__global__ __launch_bounds__(512, 1) void step(
    const float* __restrict__ obs, const int* __restrict__ mski,
    const unsigned short* __restrict__ wp, const unsigned short* __restrict__ wz,
    const float* __restrict__ bz, const float* __restrict__ b_p,
    const float* __restrict__ W_e, const float* __restrict__ b_e,
    const float* __restrict__ W_o, const float* __restrict__ b_o,
    const float* __restrict__ cur_rd, float* __restrict__ cur_wr,
    const unsigned* __restrict__ hg_rd, unsigned* __restrict__ hg_wr,
    const float* __restrict__ cs_rd, float* __restrict__ cs_wr,
    const unsigned short* __restrict__ U_rd, unsigned short* __restrict__ U_wr,
    float* __restrict__ out, int t)
{
    __shared__ __align__(16) char bufA[33280];   // cell[16][512]+pos[512] -> z[16][520]
    __shared__ __align__(16) char bufB[16384];   // list[16][512] -> x[16][328]
    __shared__ __align__(16) char bufC[8192];    // soc[16][128] -> hl[16][136]
    __shared__ int nv[16];
    short  (*cell)[512] = (short(*)[512])bufA;
    float2* pos         = (float2*)(bufA + 16384);
    float  (*z)[520]    = (float(*)[520])bufA;
    short  (*list)[512] = (short(*)[512])bufB;
    unsigned short (*x)[328] = (unsigned short(*)[328])bufB;
    float  (*soc)[128]  = (float(*)[128])bufC;
    unsigned short (*hl)[136] = (unsigned short(*)[136])bufC;

    const int bid = blockIdx.x, tid = threadIdx.x;
    const int rg = bid >> 1, ch = bid & 1;
    const int r0 = rg * 16;
    const int w = tid >> 6, lane = tid & 63;
    const int mode = (t < T_OBS) ? 0 : ((t == T_OBS) ? 1 : 2);

    // ---- P: positions (all 512 agents) ----
    {
        int j = tid;   // 512 threads cover 512 agents
        float px, py;
        if (mode == 2){
            float2 cv = ((const float2*)cur_rd)[j];
            px = cv.x; py = cv.y;
        } else {
            int tt = (mode == 0) ? t : (T_OBS - 1);
            px = obs[tt*1024 + 2*j]; py = obs[tt*1024 + 2*j + 1];
            if (isnan(px)) px = 0.f;
            if (isnan(py)) py = 0.f;
            if (mode == 1 && !mski[j]){ px = 0.f; py = 0.f; }
        }
        pos[j] = make_float2(px, py);
    }
    __syncthreads();

    // ---- cells for own 16 agents vs all j ----
    {
        int j = tid;
        float2 pj = pos[j];
        int mj = mski[j];
        #pragma unroll 4
        for (int a = 0; a < 16; ++a){
            int i = r0 + a;
            int cc = -1;
            if (mj && j != i && mski[i]){
                float rx = pj.x - pos[i].x, ry = pj.y - pos[i].y;
                if (fabsf(rx) < 32.f && fabsf(ry) < 32.f){
                    int col = (int)floorf((rx + 32.f) * 0.125f);
                    int row = (int)floorf((ry + 32.f) * 0.125f);
                    col = min(max(col, 0), 7); row = min(max(row, 0), 7);
                    cc = row*8 + col;
                }
            }
            cell[a][j] = (short)cc;
        }
    }
    __syncthreads();

    // ---- ballot compaction: wave w -> agents 2w, 2w+1 ----
    for (int s = 0; s < 2; ++s){
        int a = w*2 + s;
        int base = 0;
        for (int b = 0; b < 8; ++b){
            short cj = cell[a][b*64 + lane];
            bool val = cj >= 0;
            unsigned long long bal = __ballot(val);
            int pre = __popcll(bal & ((1ull << lane) - 1ull));
            if (val) list[a][base + pre] = (short)((b*64 + lane) | ((int)cj << 9));
            base += __popcll(bal);
        }
        if (lane == 0) nv[a] = base;
    }
    __syncthreads();

    // ---- gather U(t-1): soc[a][:] = sum_{(j,c) in list[a]} U[j][c][:] ----
    {
        const int half = lane >> 5, lq = lane & 31;
        const unsigned long long* ub = (const unsigned long long*)U_rd;
        for (int s = 0; s < 2; ++s){
            int a = w*2 + s;
            int n = (t == 0) ? 0 : nv[a];     // t=0: hidden=0 -> pooled = b_p
            float a0 = 0.f, a1 = 0.f, a2 = 0.f, a3 = 0.f;
            for (int base = 0; base < n; base += 8){
                #pragma unroll
                for (int k = 0; k < 4; ++k){
                    int e = base + 2*k + half;
                    if (e < n){
                        int pk = list[a][e];
                        unsigned long long v = ub[(pk & 511)*2048 + (pk >> 9)*32 + lq];
                        unsigned lo = (unsigned)v, hi = (unsigned)(v >> 32);
                        a0 += bf2lo(lo); a1 += bf2hi(lo);
                        a2 += bf2lo(hi); a3 += bf2hi(hi);
                    }
                }
            }
            a0 += __shfl_xor(a0, 32, 64); a1 += __shfl_xor(a1, 32, 64);
            a2 += __shfl_xor(a2, 32, 64); a3 += __shfl_xor(a3, 32, 64);
            if (half == 0){
                f32x4 sv = {a0, a1, a2, a3};
                *(f32x4*)&soc[a][lq*4] = sv;
            }
        }
    }
    __syncthreads();

    // ---- X: build x = [emb | soc | h(t-1)] (bf16, rows = own 16 agents) ----
    for (int i = tid; i < 2048; i += 512){
        int a = i >> 7, u = i & 127;
        float s = soc[a][u] + b_p[u];
        if (!mski[r0 + a]) s = 0.f;
        x[a][64 + u] = f2bf(s);
    }
    for (int i = tid; i < 1024; i += 512){
        int a = i >> 6, u = i & 63;
        float2 p = pos[r0 + a];
        float e = W_e[u*2]*p.x + W_e[u*2 + 1]*p.y + b_e[u];
        x[a][u] = f2bf(fmaxf(e, 0.f));
    }
    for (int i = tid; i < 1024; i += 512){
        int a = i >> 6, p2 = i & 63;
        *(unsigned*)&x[a][192 + 2*p2] = hg_rd[(r0 + a)*64 + p2];
    }
    // stash head base positions (pos dies when z overwrites bufA)
    float2 base0 = pos[r0 + 2*w], base1 = pos[r0 + 2*w + 1];
    __syncthreads();

    // ---- LSTM GEMM: z[16][512] = x[16][320] @ wz^T, wave w -> cols w*64..+64
    const int lrow = lane & 15, lk = (lane >> 4) * 8;
    {
        f32x4 zacc[4] = {};
        for (int ks = 0; ks < 10; ++ks){
            bf16x8 af = *(const bf16x8*)&x[lrow][ks*32 + lk];
            #pragma unroll
            for (int nt = 0; nt < 4; ++nt){
                bf16x8 b = *(const bf16x8*)(wz + (w*64 + nt*16 + lrow)*320 + ks*32 + lk);
                zacc[nt] = MFMA16(af, b, zacc[nt]);
            }
        }
        const int crow = (lane >> 4) * 4, ccol = lane & 15;
        #pragma unroll
        for (int nt = 0; nt < 4; ++nt)
            #pragma unroll
            for (int r = 0; r < 4; ++r)
                z[crow + r][w*64 + nt*16 + ccol] = zacc[nt][r];
    }
    __syncthreads();

    // ---- gates -> c,h; h -> LDS bf16 (and hg/cs writes by ch==0) ----
    for (int i = tid; i < 2048; i += 512){
        int row = i >> 7, u = i & 127;
        float zi = z[row][      u] + bz[      u];
        float zf = z[row][128 + u] + bz[128 + u];
        float zg = z[row][256 + u] + bz[256 + u];
        float zo = z[row][384 + u] + bz[384 + u];
        float ig = sigm_f(zi), fg = sigm_f(zf);
        float gv = tanh_f(zg), og = sigm_f(zo);
        int gi = (r0 + row)*128 + u;
        float cn = fg * cs_rd[gi] + ig * gv;
        float hn = og * tanh_f(cn);
        if (ch == 0) cs_wr[gi] = cn;
        hl[row][u] = f2bf(hn);
    }
    __syncthreads();
    if (ch == 0){
        for (int i = tid; i < 1024; i += 512){
            int a = i >> 6, p2 = i & 63;
            hg_wr[(r0 + a)*64 + p2] = *(const unsigned*)&hl[a][2*p2];
        }
    }

    // ---- decoder head (ch==0, wave w -> agents 2w, 2w+1) ----
    if (ch == 0 && t >= T_OBS){
        const int dec_t = t - T_OBS;
        for (int s = 0; s < 2; ++s){
            int al = 2*w + s, ag = r0 + al;
            unsigned hv = *(const unsigned*)&hl[al][2*lane];
            float h0 = bf2lo(hv), h1 = bf2hi(hv);
            float p[5];
            #pragma unroll
            for (int o = 0; o < 5; ++o)
                p[o] = W_o[o*128 + 2*lane]*h0 + W_o[o*128 + 2*lane + 1]*h1;
            #pragma unroll
            for (int sh = 32; sh; sh >>= 1)
                #pragma unroll
                for (int o = 0; o < 5; ++o) p[o] += __shfl_xor(p[o], sh, 64);
            if (lane == 0){
                float mu0 = p[0] + b_o[0], mu1 = p[1] + b_o[1];
                float s0 = __expf(p[2] + b_o[2]) + 1e-6f;
                float s1 = __expf(p[3] + b_o[3]) + 1e-6f;
                float rh = tanh_f(p[4] + b_o[4]);
                float cx, cy;
                if (t == T_OBS){ float2 b2 = s ? base1 : base0; cx = b2.x; cy = b2.y; }
                else { cx = cur_rd[ag*2]; cy = cur_rd[ag*2 + 1]; }
                if (mski[ag]){ cx += mu0; cy += mu1; }
                cur_wr[ag*2] = cx; cur_wr[ag*2 + 1] = cy;
                out[dec_t*1024 + ag*2]             = cx;
                out[dec_t*1024 + ag*2 + 1]         = cy;
                out[12288 + dec_t*1024 + ag*2]     = s0;
                out[12288 + dec_t*1024 + ag*2 + 1] = s1;
                out[24576 + dec_t*512 + ag]        = rh;
            }
        }
    }

    // ---- U(t) = W_p . h(t): own 16 rows x cells [ch*32, +32) ----
    {
        bf16x8 ak[4];
        #pragma unroll
        for (int ks = 0; ks < 4; ++ks)
            ak[ks] = *(const bf16x8*)&hl[lrow][ks*32 + lk];
        const int crow = (lane >> 4) * 4, ccol = lane & 15;
        for (int ci = 0; ci < 4; ++ci){
            const int gcell = ch*32 + w*4 + ci;
            #pragma unroll
            for (int nt = 0; nt < 8; ++nt){
                f32x4 acc = {};
                #pragma unroll
                for (int ks = 0; ks < 4; ++ks){
                    bf16x8 b = *(const bf16x8*)(wp + (nt*16 + lrow)*8192 +
                                                gcell*128 + ks*32 + lk);
                    acc = MFMA16(ak[ks], b, acc);
                }
                #pragma unroll
                for (int r = 0; r < 4; ++r)
                    U_wr[(r0 + crow + r)*8192 + gcell*128 + nt*16 + ccol]
                        = f2bf(acc[r]);
            }
        }
    }
}

extern "C" void kernel_launch(void* const* d_in, const int* in_sizes, int n_in,
                              void* d_out, int out_size, void* d_ws, size_t ws_size,
                              hipStream_t stream)
{
    const float* obs  = (const float*)d_in[0];
    const unsigned char* mraw = (const unsigned char*)d_in[1];
    const float* W_e  = (const float*)d_in[2];
    const float* b_e  = (const float*)d_in[3];
    const float* W_p  = (const float*)d_in[4];
    const float* b_p  = (const float*)d_in[5];
    const float* W_ih = (const float*)d_in[6];
    const float* W_hh = (const float*)d_in[7];
    const float* b_ih = (const float*)d_in[8];
    const float* b_hh = (const float*)d_in[9];
    const float* W_o  = (const float*)d_in[10];
    const float* b_o  = (const float*)d_in[11];
    float* out = (float*)d_out;

    char* ws = (char*)d_ws;
    unsigned short* wp_bf = (unsigned short*)(ws + WP_OFF);
    unsigned short* wz_bf = (unsigned short*)(ws + WZ_OFF);
    float* bz   = (float*)(ws + BZ_OFF);
    int*   mski = (int*)  (ws + MASK_OFF);
    float* cur[2] = { (float*)(ws + CUR0_OFF), (float*)(ws + CUR1_OFF) };
    unsigned* hg[2] = { (unsigned*)(ws + HG0_OFF), (unsigned*)(ws + HG1_OFF) };
    float* cs[2] = { (float*)(ws + CS0_OFF), (float*)(ws + CS1_OFF) };
    unsigned short* U[2] = { (unsigned short*)(ws + U0_OFF),
                             (unsigned short*)(ws + U1_OFF) };

    prep<<<512, 256, 0, stream>>>(W_p, W_ih, W_hh, b_ih, b_hh, mraw,
                                  wp_bf, wz_bf, bz, mski, hg[1], cs[1]);

    for (int t = 0; t < T_OBS + PRED; ++t){
        const int wr = t & 1, rd = wr ^ 1;
        step<<<64, 512, 0, stream>>>(obs, mski, wp_bf, wz_bf, bz, b_p,
                                     W_e, b_e, W_o, b_o,
                                     cur[rd], cur[wr], hg[rd], hg[wr],
                                     cs[rd], cs[wr], U[rd], U[wr], out, t);
    }
}

// Round 8
// 1193.539 us; speedup vs baseline: 2.2160x; 2.2160x over previous
//
#include <hip/hip_runtime.h>

#define T_OBS 8
#define PRED  12
#define NBLK  512
#define NTHR  256

typedef __attribute__((ext_vector_type(8))) short bf16x8;
typedef __attribute__((ext_vector_type(4))) float f32x4;
#define MFMA16(a,b,c) __builtin_amdgcn_mfma_f32_16x16x32_bf16((a),(b),(c),0,0,0)
#define AS __ATOMIC_RELAXED, __HIP_MEMORY_SCOPE_AGENT

// workspace offsets (bytes)
#define WP_OFF   0            // 128*8192*2 = 2097152
#define WZ_OFF   2097152      // 512*320*2  = 327680
#define BZ_OFF   2424832      // 512*4
#define MASK_OFF 2426880      // 512*4
#define CUR0_OFF 2428928      // 512*2*4
#define CUR1_OFF 2433024
#define HG_OFF   2437120      // 512*128*2 = 131072
#define U_OFF    2568192      // 512*64*128*2 = 8388608
#define BAR_OFF  10956800     // 2048*4 -> ends ~10.97 MB

// coherent cross-XCD access: relaxed agent atomics, NO fences
static __device__ __forceinline__ void st32c(void* p, unsigned v){
    __hip_atomic_store((unsigned*)p, v, AS);
}
static __device__ __forceinline__ void st64c(void* p, unsigned long long v){
    __hip_atomic_store((unsigned long long*)p, v, AS);
}
static __device__ __forceinline__ unsigned long long ld64c(const void* p){
    return __hip_atomic_load((const unsigned long long*)p, AS);
}
static __device__ __forceinline__ bf16x8 ldfragc(const unsigned short* p){
    union { unsigned long long q[2]; bf16x8 v; } u;
    u.q[0] = ld64c(p); u.q[1] = ld64c(p + 4);
    return u.v;
}

static __device__ __forceinline__ unsigned short f2bf(float x){
    union { float f; unsigned u; } v; v.f = x;
    unsigned r = v.u + 0x7fffu + ((v.u >> 16) & 1u);   // RNE
    return (unsigned short)(r >> 16);
}
static __device__ __forceinline__ unsigned pack2(float a, float b){
    return (unsigned)f2bf(a) | ((unsigned)f2bf(b) << 16);
}
static __device__ __forceinline__ float bf2lo(unsigned v){ return __uint_as_float(v << 16); }
static __device__ __forceinline__ float bf2hi(unsigned v){ return __uint_as_float(v & 0xffff0000u); }
static __device__ __forceinline__ float sigm_f(float x){ return 1.f / (1.f + __expf(-x)); }
static __device__ __forceinline__ float tanh_f(float x){
    float e = __expf(-2.f * fabsf(x));
    float t = (1.f - e) / (1.f + e);
    return copysignf(t, x);
}

// two-level grid barrier: relaxed monotonic counters only (no cache flushes).
// __syncthreads() drains every wave's vmcnt before arrival (HIP semantics).
static __device__ __forceinline__ void gridbar(int* bar, int bid, int& gen){
    __syncthreads();
    if (threadIdx.x == 0){
        gen++;
        int p = __hip_atomic_fetch_add(&bar[32 + (bid >> 3)*16], 1, AS);
        if ((p & 7) == 7){
            int q = __hip_atomic_fetch_add(&bar[16], 1, AS);
            if ((q & 63) == 63)
                __hip_atomic_store(&bar[0], gen, AS);
        }
        int spins = 0;
        while (__hip_atomic_load(&bar[0], AS) < gen){
            __builtin_amdgcn_s_sleep(1);
            if (++spins > (1 << 22)) break;   // safety bail: no hang
        }
        asm volatile("" ::: "memory");
    }
    __syncthreads();
}

__global__ void bar_init(int* bar){
    int i = blockIdx.x * 1024 + threadIdx.x;
    if (i < 2048) bar[i] = 0;
}

struct P1S { unsigned short ustage[16][512]; };   // 16384
struct P2S {
    float2 pos[512];          // 4096
    short  cell[512];         // 1024
    short  list[512];         // 1024
    float  socp[8][128];      // 4096
    unsigned short x[352];    // 704 (16B-aligned start)
    float  z[512];            // 2048
};
union __align__(16) SB { P1S p1; P2S p2; };

__global__ __launch_bounds__(NTHR, 2) void social_persist(
    const float* __restrict__ obs, const unsigned char* __restrict__ mraw,
    const float* __restrict__ W_e, const float* __restrict__ b_e,
    const float* __restrict__ Wp,  const float* __restrict__ b_p,
    const float* __restrict__ Wih, const float* __restrict__ Whh,
    const float* __restrict__ bih, const float* __restrict__ bhh,
    const float* __restrict__ W_o, const float* __restrict__ b_o,
    unsigned short* wp_bf, unsigned short* wz, float* bz, int* mski,
    float* cur0, float* cur1, unsigned short* hg, unsigned short* U,
    int* bar, float* out)
{
    __shared__ SB sb;
    __shared__ unsigned short hl[128];   // h(t-1) bf16, block-persistent
    __shared__ float hf[128];            // h(t) f32 (head)
    __shared__ int nvS, mflagA, mflagB;

    const int bid = blockIdx.x, tid = threadIdx.x;
    const int w = tid >> 6, lane = tid & 63;
    const int lrow = lane & 15, lk = (lane >> 4) * 8;
    const int crow = (lane >> 4) * 4, ccol = lane & 15;
    int gen = 0;
    float c_reg = 0.f;                   // cell state, unit=tid (tid<128)
    float cx_r = 0.f, cy_r = 0.f;        // cur (tid==0)

    // ---------------- prep: weights->bf16 (coherent), init ----------------
    {
        const int i0 = bid * NTHR + tid, stride = NBLK * NTHR;     // 131072
        for (int i = i0; i < 524288; i += stride)
            st32c((unsigned*)wp_bf + i, pack2(Wp[2*i], Wp[2*i + 1]));
        for (int i = i0; i < 81920; i += stride){
            int n = (2*i) / 320, k = (2*i) - n*320;
            float w0 = (k < 192)     ? Wih[n*192 + k]     : Whh[n*128 + k - 192];
            float w1 = (k + 1 < 192) ? Wih[n*192 + k + 1] : Whh[n*128 + k + 1 - 192];
            st32c((unsigned*)wz + i, pack2(w0, w1));
        }
        for (int i = i0; i < 512; i += stride)
            st32c((unsigned*)bz + i, __float_as_uint(bih[i] + bhh[i]));
        for (int i = i0; i < 16384; i += stride)                   // hg = 0
            st64c((unsigned long long*)hg + i, 0ull);
        if (tid < 128){ hl[tid] = 0; hf[tid] = 0.f; }
        if (bid == 0){
            if (tid == 0){ mflagA = 0; mflagB = 0; }
            __syncthreads();
            for (int j = tid; j < 512; j += NTHR){
                unsigned char b = mraw[j];
                if (b && (j & 3))        atomicAdd(&mflagA, 1);
                if (b && ((j & 7) == 4)) atomicAdd(&mflagB, 1);
            }
            __syncthreads();
            for (int j = tid; j < 512; j += NTHR){
                int v;
                if (mflagA)      v = mraw[j] ? 1 : 0;
                else if (mflagB) v = ((const int*)mraw)[j] ? 1 : 0;
                else             v = ((const long long*)mraw)[j] ? 1 : 0;
                st32c(mski + j, (unsigned)v);
            }
        }
    }
    gridbar(bar, bid, gen);

    for (int t = 0; t < T_OBS + PRED; ++t){
        // ============ P1: U[j][c][:] = W_c . h(t-1)[j] =======================
        // block (rg = bid>>4, cs = bid&15): rows rg*16..+16, cells cs*4..+4
        // stride-16 same-cs blocks land on the same XCD -> W_p slice L2-warm.
        {
            const int rg = bid >> 4, cs = bid & 15, r0 = rg * 16;
            bf16x8 a[4];
            #pragma unroll
            for (int ks = 0; ks < 4; ++ks)
                a[ks] = ldfragc(hg + (r0 + lrow)*128 + ks*32 + lk);
            const int cell = cs*4 + w;           // wave owns one cell
            f32x4 acc[8] = {};
            #pragma unroll
            for (int nt = 0; nt < 8; ++nt)
                #pragma unroll
                for (int ks = 0; ks < 4; ++ks)
                    acc[nt] = MFMA16(a[ks],
                        *(const bf16x8*)(wp_bf + (nt*16 + lrow)*8192 +
                                         cell*128 + ks*32 + lk), acc[nt]);
            #pragma unroll
            for (int nt = 0; nt < 8; ++nt)
                #pragma unroll
                for (int r = 0; r < 4; ++r)
                    sb.p1.ustage[crow + r][w*128 + nt*16 + ccol] = f2bf(acc[nt][r]);
            __syncthreads();
            const unsigned long long* us = (const unsigned long long*)sb.p1.ustage;
            unsigned long long* ud = (unsigned long long*)U;
            for (int e = tid; e < 2048; e += NTHR){
                int row = e >> 7, o = e & 127;
                st64c(ud + (long long)(r0 + row)*2048 + cs*128 + o, us[row*128 + o]);
            }
        }
        gridbar(bar, bid, gen);

        // ============ P2: agent = bid ========================================
        {
            P2S& s2 = sb.p2;
            const int mode = (t < T_OBS) ? 0 : ((t == T_OBS) ? 1 : 2);
            const float* cur_rd = ((t - 1) & 1) ? cur1 : cur0;
            float* cur_wr = (t & 1) ? cur1 : cur0;
            // positions
            for (int s = 0; s < 2; ++s){
                int j = tid + s*256;
                float px, py;
                if (mode == 2){
                    union { float f[2]; unsigned long long q; } cu;
                    cu.q = ld64c((const unsigned long long*)cur_rd + j);
                    px = cu.f[0]; py = cu.f[1];
                } else {
                    int tt = (mode == 0) ? t : (T_OBS - 1);
                    px = obs[tt*1024 + 2*j]; py = obs[tt*1024 + 2*j + 1];
                    if (isnan(px)) px = 0.f;
                    if (isnan(py)) py = 0.f;
                    if (mode == 1 && !mski[j]){ px = 0.f; py = 0.f; }
                }
                s2.pos[j] = make_float2(px, py);
            }
            __syncthreads();
            const float2 pi = s2.pos[bid];
            const int vi = mski[bid];
            for (int s = 0; s < 2; ++s){
                int j = tid + s*256;
                int cc = -1;
                if (vi && j != bid && mski[j]){
                    float rx = s2.pos[j].x - pi.x, ry = s2.pos[j].y - pi.y;
                    if (fabsf(rx) < 32.f && fabsf(ry) < 32.f){
                        int col = (int)floorf((rx + 32.f) * 0.125f);
                        int row = (int)floorf((ry + 32.f) * 0.125f);
                        col = min(max(col, 0), 7); row = min(max(row, 0), 7);
                        cc = row*8 + col;
                    }
                }
                s2.cell[j] = (short)cc;
            }
            __syncthreads();
            if (tid < 64){
                int base = 0;
                for (int b = 0; b < 8; ++b){
                    short cj = s2.cell[b*64 + tid];
                    bool val = cj >= 0;
                    unsigned long long bal = __ballot(val);
                    int pre = __popcll(bal & ((1ull << tid) - 1ull));
                    if (val) s2.list[base + pre] = (short)((b*64 + tid) | ((int)cj << 9));
                    base += __popcll(bal);
                }
                if (tid == 0) nvS = base;
            }
            __syncthreads();
            const int nv = nvS;
            // gather: 8 half-wave slots x unroll-4 -> 32 entries in flight
            {
                const int slot = tid >> 5, lq = tid & 31;
                const unsigned long long* ub = (const unsigned long long*)U;
                float a0 = 0.f, a1 = 0.f, a2 = 0.f, a3 = 0.f;
                int b4 = 0;
                for (; b4 + 32 <= nv; b4 += 32){
                    int p0 = s2.list[b4      + slot];
                    int p1 = s2.list[b4 + 8  + slot];
                    int p2 = s2.list[b4 + 16 + slot];
                    int p3 = s2.list[b4 + 24 + slot];
                    unsigned long long v0 = ld64c(ub + (p0 & 511)*2048 + (p0 >> 9)*32 + lq);
                    unsigned long long v1 = ld64c(ub + (p1 & 511)*2048 + (p1 >> 9)*32 + lq);
                    unsigned long long v2 = ld64c(ub + (p2 & 511)*2048 + (p2 >> 9)*32 + lq);
                    unsigned long long v3 = ld64c(ub + (p3 & 511)*2048 + (p3 >> 9)*32 + lq);
                    unsigned lo, hi;
                    lo = (unsigned)v0; hi = (unsigned)(v0 >> 32);
                    a0 += bf2lo(lo); a1 += bf2hi(lo); a2 += bf2lo(hi); a3 += bf2hi(hi);
                    lo = (unsigned)v1; hi = (unsigned)(v1 >> 32);
                    a0 += bf2lo(lo); a1 += bf2hi(lo); a2 += bf2lo(hi); a3 += bf2hi(hi);
                    lo = (unsigned)v2; hi = (unsigned)(v2 >> 32);
                    a0 += bf2lo(lo); a1 += bf2hi(lo); a2 += bf2lo(hi); a3 += bf2hi(hi);
                    lo = (unsigned)v3; hi = (unsigned)(v3 >> 32);
                    a0 += bf2lo(lo); a1 += bf2hi(lo); a2 += bf2lo(hi); a3 += bf2hi(hi);
                }
                for (; b4 < nv; b4 += 8){
                    int e = b4 + slot;
                    if (e < nv){
                        int pk = s2.list[e];
                        unsigned long long v = ld64c(ub + (pk & 511)*2048 + (pk >> 9)*32 + lq);
                        unsigned lo = (unsigned)v, hi = (unsigned)(v >> 32);
                        a0 += bf2lo(lo); a1 += bf2hi(lo); a2 += bf2lo(hi); a3 += bf2hi(hi);
                    }
                }
                f32x4 sv = {a0, a1, a2, a3};
                *(f32x4*)&s2.socp[slot][lq*4] = sv;
            }
            __syncthreads();
            // x = [emb | soc | h(t-1)]
            if (tid < 128){
                float s = b_p[tid];
                #pragma unroll
                for (int p = 0; p < 8; ++p) s += s2.socp[p][tid];
                if (!vi) s = 0.f;
                s2.x[64 + tid] = f2bf(s);
            }
            if (tid < 64){
                float e = W_e[tid*2]*pi.x + W_e[tid*2 + 1]*pi.y + b_e[tid];
                s2.x[tid] = f2bf(fmaxf(e, 0.f));
            }
            if (tid < 128) s2.x[192 + tid] = hl[tid];
            __syncthreads();
            // LSTM: z[512] = x @ wz^T via broadcast-M16 MFMA (wave w: cols w*128..+128)
            {
                f32x4 zac[8] = {};
                for (int ks = 0; ks < 10; ++ks){
                    bf16x8 xa = *(const bf16x8*)&s2.x[ks*32 + lk];   // LDS broadcast
                    #pragma unroll
                    for (int nt = 0; nt < 8; ++nt)
                        zac[nt] = MFMA16(xa,
                            *(const bf16x8*)(wz + (w*128 + nt*16 + lrow)*320 +
                                             ks*32 + lk), zac[nt]);
                }
                if (lane < 16)
                    #pragma unroll
                    for (int nt = 0; nt < 8; ++nt)
                        s2.z[w*128 + nt*16 + lane] = zac[nt][0];
            }
            __syncthreads();
            // gates -> c (regs), h -> hl/hf + coherent hg
            if (tid < 128){
                float zi = s2.z[      tid] + bz[      tid];
                float zf = s2.z[128 + tid] + bz[128 + tid];
                float zg = s2.z[256 + tid] + bz[256 + tid];
                float zo = s2.z[384 + tid] + bz[384 + tid];
                float ig = sigm_f(zi), fg = sigm_f(zf);
                float gv = tanh_f(zg), og = sigm_f(zo);
                c_reg = fg * c_reg + ig * gv;
                float hn = og * tanh_f(c_reg);
                hf[tid] = hn; hl[tid] = f2bf(hn);
            }
            __syncthreads();
            if (tid < 64)
                st32c((unsigned*)hg + bid*64 + tid, pack2(hf[2*tid], hf[2*tid + 1]));
            // decoder head
            if (t >= T_OBS && tid < 64){
                const int dec_t = t - T_OBS;
                float h0 = hf[2*tid], h1 = hf[2*tid + 1];
                float p[5];
                #pragma unroll
                for (int o = 0; o < 5; ++o)
                    p[o] = W_o[o*128 + 2*tid]*h0 + W_o[o*128 + 2*tid + 1]*h1;
                #pragma unroll
                for (int sh = 32; sh; sh >>= 1)
                    #pragma unroll
                    for (int o = 0; o < 5; ++o) p[o] += __shfl_xor(p[o], sh, 64);
                if (tid == 0){
                    float mu0 = p[0] + b_o[0], mu1 = p[1] + b_o[1];
                    float s0 = __expf(p[2] + b_o[2]) + 1e-6f;
                    float s1 = __expf(p[3] + b_o[3]) + 1e-6f;
                    float rh = tanh_f(p[4] + b_o[4]);
                    if (t == T_OBS){ cx_r = pi.x; cy_r = pi.y; }  // masked obs[7]
                    if (vi){ cx_r += mu0; cy_r += mu1; }
                    union { float f[2]; unsigned long long q; } cu;
                    cu.f[0] = cx_r; cu.f[1] = cy_r;
                    st64c((unsigned long long*)cur_wr + bid, cu.q);
                    out[dec_t*1024 + bid*2]             = cx_r;
                    out[dec_t*1024 + bid*2 + 1]         = cy_r;
                    out[12288 + dec_t*1024 + bid*2]     = s0;
                    out[12288 + dec_t*1024 + bid*2 + 1] = s1;
                    out[24576 + dec_t*512 + bid]        = rh;
                }
            }
        }
        gridbar(bar, bid, gen);
    }
}

extern "C" void kernel_launch(void* const* d_in, const int* in_sizes, int n_in,
                              void* d_out, int out_size, void* d_ws, size_t ws_size,
                              hipStream_t stream)
{
    const float* obs  = (const float*)d_in[0];
    const unsigned char* mraw = (const unsigned char*)d_in[1];
    const float* W_e  = (const float*)d_in[2];
    const float* b_e  = (const float*)d_in[3];
    const float* W_p  = (const float*)d_in[4];
    const float* b_p  = (const float*)d_in[5];
    const float* W_ih = (const float*)d_in[6];
    const float* W_hh = (const float*)d_in[7];
    const float* b_ih = (const float*)d_in[8];
    const float* b_hh = (const float*)d_in[9];
    const float* W_o  = (const float*)d_in[10];
    const float* b_o  = (const float*)d_in[11];
    float* out = (float*)d_out;

    char* ws = (char*)d_ws;
    unsigned short* wp_bf = (unsigned short*)(ws + WP_OFF);
    unsigned short* wz_bf = (unsigned short*)(ws + WZ_OFF);
    float* bz   = (float*)(ws + BZ_OFF);
    int*   mski = (int*)  (ws + MASK_OFF);
    float* cur0 = (float*)(ws + CUR0_OFF);
    float* cur1 = (float*)(ws + CUR1_OFF);
    unsigned short* hg = (unsigned short*)(ws + HG_OFF);
    unsigned short* U  = (unsigned short*)(ws + U_OFF);
    int*   bar  = (int*)  (ws + BAR_OFF);

    bar_init<<<2, 1024, 0, stream>>>(bar);
    social_persist<<<NBLK, NTHR, 0, stream>>>(
        obs, mraw, W_e, b_e, W_p, b_p, W_ih, W_hh, b_ih, b_hh, W_o, b_o,
        wp_bf, wz_bf, bz, mski, cur0, cur1, hg, U, bar, out);
}

// Round 9
// 733.649 us; speedup vs baseline: 3.6050x; 1.6269x over previous
//
#include <hip/hip_runtime.h>

#define T_OBS 8
#define PRED  12

typedef __attribute__((ext_vector_type(8))) short bf16x8;
typedef __attribute__((ext_vector_type(4))) float f32x4;
#define MFMA16(a,b,c) __builtin_amdgcn_mfma_f32_16x16x32_bf16((a),(b),(c),0,0,0)

// workspace offsets (bytes)
#define WP_OFF   0            // 128*8192*2 = 2097152
#define WZ_OFF   2097152      // 512*320*2  = 327680
#define BZ_OFF   2424832      // 512*4
#define MASK_OFF 2426880      // 512*4
#define CUR0_OFF 2428928      // 512*2*4
#define CUR1_OFF 2433024
#define HG_OFF   2437120      // 512*128*2  = 131072
#define CST_OFF  2568192      // 512*128*4  = 262144
#define U_OFF    2830336      // 512*64*128*2 = 8388608 -> ends ~11.2 MB

static __device__ __forceinline__ unsigned short f2bf(float x){
    union { float f; unsigned u; } v; v.f = x;
    unsigned r = v.u + 0x7fffu + ((v.u >> 16) & 1u);   // RNE
    return (unsigned short)(r >> 16);
}
static __device__ __forceinline__ unsigned pack2(float a, float b){
    return (unsigned)f2bf(a) | ((unsigned)f2bf(b) << 16);
}
static __device__ __forceinline__ float bf2lo(unsigned v){ return __uint_as_float(v << 16); }
static __device__ __forceinline__ float bf2hi(unsigned v){ return __uint_as_float(v & 0xffff0000u); }
static __device__ __forceinline__ float sigm_f(float x){ return 1.f / (1.f + __expf(-x)); }
static __device__ __forceinline__ float tanh_f(float x){
    float e = __expf(-2.f * fabsf(x));
    float t = (1.f - e) / (1.f + e);
    return copysignf(t, x);
}

// ---------------- prep: weights->bf16, zero state, mask decode ----------------
__global__ __launch_bounds__(256) void prep(
    const float* __restrict__ Wp, const float* __restrict__ Wih,
    const float* __restrict__ Whh, const float* __restrict__ bih,
    const float* __restrict__ bhh, const unsigned char* __restrict__ mraw,
    unsigned short* __restrict__ wp_bf, unsigned short* __restrict__ wz,
    float* __restrict__ bz, int* __restrict__ mski,
    unsigned* __restrict__ hg32, float* __restrict__ cst)
{
    __shared__ int mflagA, mflagB;
    const int bid = blockIdx.x, tid = threadIdx.x;
    const int i0 = bid * 256 + tid, stride = 512 * 256;
    for (int i = i0; i < 524288; i += stride)
        ((unsigned*)wp_bf)[i] = pack2(Wp[2*i], Wp[2*i + 1]);
    for (int i = i0; i < 81920; i += stride){
        int n = (2*i) / 320, k = (2*i) - n*320;
        float w0 = (k < 192)     ? Wih[n*192 + k]     : Whh[n*128 + k - 192];
        float w1 = (k + 1 < 192) ? Wih[n*192 + k + 1] : Whh[n*128 + k + 1 - 192];
        ((unsigned*)wz)[i] = pack2(w0, w1);
    }
    for (int i = i0; i < 512; i += stride) bz[i] = bih[i] + bhh[i];
    for (int i = i0; i < 32768; i += stride) hg32[i] = 0u;     // h(-1) = 0
    for (int i = i0; i < 65536; i += stride) cst[i] = 0.f;     // c(-1) = 0
    if (bid == 0){
        if (tid == 0){ mflagA = 0; mflagB = 0; }
        __syncthreads();
        for (int j = tid; j < 512; j += 256){
            unsigned char b = mraw[j];
            if (b && (j & 3))        atomicAdd(&mflagA, 1);
            if (b && ((j & 7) == 4)) atomicAdd(&mflagB, 1);
        }
        __syncthreads();
        for (int j = tid; j < 512; j += 256){
            int v;
            if (mflagA)      v = mraw[j] ? 1 : 0;
            else if (mflagB) v = ((const int*)mraw)[j] ? 1 : 0;
            else             v = ((const long long*)mraw)[j] ? 1 : 0;
            mski[j] = v;
        }
    }
}

// ---------------- KU: U-GEMM  U[j][c][:] = W_c . h(t-1)[j] --------------------
// block (mq 0..15, cp 0..31): rows mq*32..+32, cells {2cp, 2cp+1}
__global__ __launch_bounds__(256) void ku(
    const unsigned short* __restrict__ hg,
    const unsigned short* __restrict__ wp_bf,
    unsigned short* __restrict__ U)
{
    __shared__ unsigned short ustage[32][256];   // 16 KB
    const int bid = blockIdx.x, tid = threadIdx.x;
    const int mq = bid >> 5, cp = bid & 31;
    const int r0 = mq * 32;
    const int w = tid >> 6, lane = tid & 63;
    const int msub = w & 1, nq = w >> 1;
    const int lrow = lane & 15, lk = (lane >> 4) * 8;
    f32x4 acc[2][4] = {};
    #pragma unroll
    for (int ks = 0; ks < 4; ++ks){
        bf16x8 a = *(const bf16x8*)(hg + (r0 + msub*16 + lrow)*128 + ks*32 + lk);
        #pragma unroll
        for (int cell = 0; cell < 2; ++cell){
            #pragma unroll
            for (int ntl = 0; ntl < 4; ++ntl){
                const unsigned short* bp = wp_bf +
                    ((nq*4 + ntl)*16 + lrow)*8192 + (2*cp + cell)*128 + ks*32 + lk;
                acc[cell][ntl] = MFMA16(a, *(const bf16x8*)bp, acc[cell][ntl]);
            }
        }
    }
    const int crow = (lane >> 4) * 4, ccol = lane & 15;
    #pragma unroll
    for (int cell = 0; cell < 2; ++cell)
        #pragma unroll
        for (int ntl = 0; ntl < 4; ++ntl)
            #pragma unroll
            for (int r = 0; r < 4; ++r)
                ustage[msub*16 + crow + r][cell*128 + (nq*4 + ntl)*16 + ccol]
                    = f2bf(acc[cell][ntl][r]);
    __syncthreads();
    for (int e = tid; e < 1024; e += 256){
        int r = e >> 5, o = e & 31;
        *(ulonglong2*)((char*)U + ((long long)(r0 + r)*64 + 2*cp)*256 + o*16)
            = *(const ulonglong2*)&ustage[r][o*8];
    }
}

// ---------------- KGL: gather + soc/emb + LSTM + head (4 agents/block) --------
__global__ __launch_bounds__(512, 1) void kgl(
    const float* __restrict__ obs, const int* __restrict__ mski,
    const unsigned short* __restrict__ U, const unsigned short* __restrict__ wz,
    const float* __restrict__ bz, const float* __restrict__ b_p,
    const float* __restrict__ W_e, const float* __restrict__ b_e,
    const float* __restrict__ W_o, const float* __restrict__ b_o,
    const float* __restrict__ cur_rd, float* __restrict__ cur_wr,
    unsigned short* __restrict__ hg, float* __restrict__ cst,
    float* __restrict__ out, int t)
{
    __shared__ float2 pos[512];            // 4 KB
    __shared__ short  cellm[4][512];       // 4 KB
    __shared__ short  lst[4][512];         // 4 KB
    __shared__ int    nv[4];
    __shared__ float  socp[4][4][128];     // 8 KB
    __shared__ unsigned short x[16][328];  // 10.5 KB (rows 4-15 scratch for MFMA)
    __shared__ float  z[4][512];           // 8 KB
    __shared__ float  hf[4][128];          // 2 KB

    const int bid = blockIdx.x, tid = threadIdx.x;
    const int a0 = bid * 4;
    const int w = tid >> 6, lane = tid & 63;
    const int mode = (t < T_OBS) ? 0 : ((t == T_OBS) ? 1 : 2);

    // ---- positions (all 512 agents) ----
    {
        int j = tid;
        float px, py;
        if (mode == 2){
            float2 cv = ((const float2*)cur_rd)[j];
            px = cv.x; py = cv.y;
        } else {
            int tt = (mode == 0) ? t : (T_OBS - 1);
            px = obs[tt*1024 + 2*j]; py = obs[tt*1024 + 2*j + 1];
            if (isnan(px)) px = 0.f;
            if (isnan(py)) py = 0.f;
            if (mode == 1 && !mski[j]){ px = 0.f; py = 0.f; }
        }
        pos[j] = make_float2(px, py);
    }
    __syncthreads();

    // ---- cells: own 4 agents vs all j ----
    {
        int j = tid;
        float2 pj = pos[j];
        int mj = mski[j];
        #pragma unroll
        for (int a = 0; a < 4; ++a){
            int i = a0 + a;
            int cc = -1;
            if (mj && j != i && mski[i]){
                float rx = pj.x - pos[i].x, ry = pj.y - pos[i].y;
                if (fabsf(rx) < 32.f && fabsf(ry) < 32.f){
                    int col = (int)floorf((rx + 32.f) * 0.125f);
                    int row = (int)floorf((ry + 32.f) * 0.125f);
                    col = min(max(col, 0), 7); row = min(max(row, 0), 7);
                    cc = row*8 + col;
                }
            }
            cellm[a][j] = (short)cc;
        }
    }
    __syncthreads();

    // ---- ballot compaction: wave w (<4) -> agent w ----
    if (w < 4){
        int base = 0;
        for (int b = 0; b < 8; ++b){
            short cj = cellm[w][b*64 + lane];
            bool val = cj >= 0;
            unsigned long long bal = __ballot(val);
            int pre = __popcll(bal & ((1ull << lane) - 1ull));
            if (val) lst[w][base + pre] = (short)((b*64 + lane) | ((int)cj << 9));
            base += __popcll(bal);
        }
        if (lane == 0) nv[w] = base;
    }
    __syncthreads();

    // ---- gather U: agent al, 4 quarter-slots x unroll-4 (16 loads in flight) --
    {
        const int al = w & 3, sw = ((w >> 2) << 1) | (lane >> 5), lq = lane & 31;
        const int n = (t == 0) ? 0 : nv[al];
        const unsigned long long* ub = (const unsigned long long*)U;
        float s0 = 0.f, s1 = 0.f, s2 = 0.f, s3 = 0.f;
        int b4 = 0;
        for (; b4 + 16 <= n; b4 += 16){
            int p0 = lst[al][b4      + sw];
            int p1 = lst[al][b4 + 4  + sw];
            int p2 = lst[al][b4 + 8  + sw];
            int p3 = lst[al][b4 + 12 + sw];
            unsigned long long v0 = ub[(p0 & 511)*2048 + (p0 >> 9)*32 + lq];
            unsigned long long v1 = ub[(p1 & 511)*2048 + (p1 >> 9)*32 + lq];
            unsigned long long v2 = ub[(p2 & 511)*2048 + (p2 >> 9)*32 + lq];
            unsigned long long v3 = ub[(p3 & 511)*2048 + (p3 >> 9)*32 + lq];
            unsigned lo, hi;
            lo = (unsigned)v0; hi = (unsigned)(v0 >> 32);
            s0 += bf2lo(lo); s1 += bf2hi(lo); s2 += bf2lo(hi); s3 += bf2hi(hi);
            lo = (unsigned)v1; hi = (unsigned)(v1 >> 32);
            s0 += bf2lo(lo); s1 += bf2hi(lo); s2 += bf2lo(hi); s3 += bf2hi(hi);
            lo = (unsigned)v2; hi = (unsigned)(v2 >> 32);
            s0 += bf2lo(lo); s1 += bf2hi(lo); s2 += bf2lo(hi); s3 += bf2hi(hi);
            lo = (unsigned)v3; hi = (unsigned)(v3 >> 32);
            s0 += bf2lo(lo); s1 += bf2hi(lo); s2 += bf2lo(hi); s3 += bf2hi(hi);
        }
        for (; b4 < n; b4 += 4){
            int e = b4 + sw;
            if (e < n){
                int pk = lst[al][e];
                unsigned long long v = ub[(pk & 511)*2048 + (pk >> 9)*32 + lq];
                unsigned lo = (unsigned)v, hi = (unsigned)(v >> 32);
                s0 += bf2lo(lo); s1 += bf2hi(lo); s2 += bf2lo(hi); s3 += bf2hi(hi);
            }
        }
        f32x4 sv = {s0, s1, s2, s3};
        *(f32x4*)&socp[al][sw][lq*4] = sv;
    }
    __syncthreads();

    // ---- x = [emb | soc | h(t-1)] for own 4 agents ----
    {
        int al = tid >> 7, u = tid & 127;
        float s = b_p[u] + socp[al][0][u] + socp[al][1][u]
                         + socp[al][2][u] + socp[al][3][u];
        if (!mski[a0 + al]) s = 0.f;
        x[al][64 + u] = f2bf(s);
    }
    if (tid < 256){
        int al = tid >> 6, u = tid & 63;
        float2 p = pos[a0 + al];
        float e = W_e[u*2]*p.x + W_e[u*2 + 1]*p.y + b_e[u];
        x[al][u] = f2bf(fmaxf(e, 0.f));
    }
    if (tid < 256){
        int al = tid >> 6, p2 = tid & 63;
        *(unsigned*)&x[al][192 + 2*p2] = ((const unsigned*)hg)[(a0 + al)*64 + p2];
    }
    __syncthreads();

    // ---- LSTM GEMM: z[4][512] = x[4][320] @ wz^T (wave w: cols w*64..+64) ----
    const int lrow = lane & 15, lk = (lane >> 4) * 8;
    {
        f32x4 zac[4] = {};
        #pragma unroll
        for (int ks = 0; ks < 10; ++ks){
            bf16x8 xa = *(const bf16x8*)&x[lrow][ks*32 + lk];
            #pragma unroll
            for (int nt = 0; nt < 4; ++nt)
                zac[nt] = MFMA16(xa,
                    *(const bf16x8*)(wz + (w*64 + nt*16 + lrow)*320 + ks*32 + lk),
                    zac[nt]);
        }
        if (lane < 16){   // crow==0 lanes hold C rows 0..3 = the 4 real agents
            #pragma unroll
            for (int nt = 0; nt < 4; ++nt)
                #pragma unroll
                for (int r = 0; r < 4; ++r)
                    z[r][w*64 + nt*16 + lane] = zac[nt][r];
        }
    }
    __syncthreads();

    // ---- gates -> c (global, block-owned), h -> hf ----
    {
        int al = tid >> 7, u = tid & 127;
        float zi = z[al][      u] + bz[      u];
        float zf = z[al][128 + u] + bz[128 + u];
        float zg = z[al][256 + u] + bz[256 + u];
        float zo = z[al][384 + u] + bz[384 + u];
        float ig = sigm_f(zi), fg = sigm_f(zf);
        float gv = tanh_f(zg), og = sigm_f(zo);
        int gi = (a0 + al)*128 + u;
        float cn = fg * cst[gi] + ig * gv;
        float hn = og * tanh_f(cn);
        cst[gi] = cn;
        hf[al][u] = hn;
    }
    __syncthreads();
    if (tid < 256){
        int al = tid >> 6, p2 = tid & 63;
        ((unsigned*)hg)[(a0 + al)*64 + p2] = pack2(hf[al][2*p2], hf[al][2*p2 + 1]);
    }

    // ---- decoder head: wave w (<4) -> agent w ----
    if (t >= T_OBS && w < 4){
        const int dec_t = t - T_OBS;
        const int ag = a0 + w;
        float h0 = hf[w][2*lane], h1 = hf[w][2*lane + 1];
        float p[5];
        #pragma unroll
        for (int o = 0; o < 5; ++o)
            p[o] = W_o[o*128 + 2*lane]*h0 + W_o[o*128 + 2*lane + 1]*h1;
        #pragma unroll
        for (int sh = 32; sh; sh >>= 1)
            #pragma unroll
            for (int o = 0; o < 5; ++o) p[o] += __shfl_xor(p[o], sh, 64);
        if (lane == 0){
            float mu0 = p[0] + b_o[0], mu1 = p[1] + b_o[1];
            float s0 = __expf(p[2] + b_o[2]) + 1e-6f;
            float s1 = __expf(p[3] + b_o[3]) + 1e-6f;
            float rh = tanh_f(p[4] + b_o[4]);
            float2 pi2 = pos[ag];        // = cur(t-1) (mode2) or masked obs[7] (mode1)
            float cx = pi2.x, cy = pi2.y;
            if (mski[ag]){ cx += mu0; cy += mu1; }
            cur_wr[ag*2] = cx; cur_wr[ag*2 + 1] = cy;
            out[dec_t*1024 + ag*2]             = cx;
            out[dec_t*1024 + ag*2 + 1]         = cy;
            out[12288 + dec_t*1024 + ag*2]     = s0;
            out[12288 + dec_t*1024 + ag*2 + 1] = s1;
            out[24576 + dec_t*512 + ag]        = rh;
        }
    }
}

extern "C" void kernel_launch(void* const* d_in, const int* in_sizes, int n_in,
                              void* d_out, int out_size, void* d_ws, size_t ws_size,
                              hipStream_t stream)
{
    const float* obs  = (const float*)d_in[0];
    const unsigned char* mraw = (const unsigned char*)d_in[1];
    const float* W_e  = (const float*)d_in[2];
    const float* b_e  = (const float*)d_in[3];
    const float* W_p  = (const float*)d_in[4];
    const float* b_p  = (const float*)d_in[5];
    const float* W_ih = (const float*)d_in[6];
    const float* W_hh = (const float*)d_in[7];
    const float* b_ih = (const float*)d_in[8];
    const float* b_hh = (const float*)d_in[9];
    const float* W_o  = (const float*)d_in[10];
    const float* b_o  = (const float*)d_in[11];
    float* out = (float*)d_out;

    char* ws = (char*)d_ws;
    unsigned short* wp_bf = (unsigned short*)(ws + WP_OFF);
    unsigned short* wz_bf = (unsigned short*)(ws + WZ_OFF);
    float* bz   = (float*)(ws + BZ_OFF);
    int*   mski = (int*)  (ws + MASK_OFF);
    float* cur[2] = { (float*)(ws + CUR0_OFF), (float*)(ws + CUR1_OFF) };
    unsigned short* hg = (unsigned short*)(ws + HG_OFF);
    float* cst  = (float*)(ws + CST_OFF);
    unsigned short* U  = (unsigned short*)(ws + U_OFF);

    prep<<<512, 256, 0, stream>>>(W_p, W_ih, W_hh, b_ih, b_hh, mraw,
                                  wp_bf, wz_bf, bz, mski, (unsigned*)hg, cst);

    for (int t = 0; t < T_OBS + PRED; ++t){
        if (t > 0)
            ku<<<512, 256, 0, stream>>>(hg, wp_bf, U);
        kgl<<<128, 512, 0, stream>>>(obs, mski, U, wz_bf, bz, b_p,
                                     W_e, b_e, W_o, b_o,
                                     cur[(t + 1) & 1], cur[t & 1],
                                     hg, cst, out, t);
    }
}

// Round 10
// 678.371 us; speedup vs baseline: 3.8988x; 1.0815x over previous
//
#include <hip/hip_runtime.h>

#define T_OBS 8
#define PRED  12

typedef __attribute__((ext_vector_type(8))) short bf16x8;
typedef __attribute__((ext_vector_type(4))) float f32x4;
#define MFMA16(a,b,c) __builtin_amdgcn_mfma_f32_16x16x32_bf16((a),(b),(c),0,0,0)

// workspace offsets (bytes)
#define WP_OFF   0            // 128*8192*2 = 2097152
#define WZ_OFF   2097152      // 512*320*2  = 327680
#define BZ_OFF   2424832      // 512*4
#define MASK_OFF 2426880      // 512*4
#define CUR0_OFF 2428928      // 512*2*4
#define CUR1_OFF 2433024
#define HG_OFF   2437120      // 512*128*2  = 131072
#define CST_OFF  2568192      // 512*128*4  = 262144
#define U_OFF    2830336      // 512*64*128*2 = 8388608 -> ends ~11.2 MB

static __device__ __forceinline__ unsigned short f2bf(float x){
    union { float f; unsigned u; } v; v.f = x;
    unsigned r = v.u + 0x7fffu + ((v.u >> 16) & 1u);   // RNE
    return (unsigned short)(r >> 16);
}
static __device__ __forceinline__ unsigned pack2(float a, float b){
    return (unsigned)f2bf(a) | ((unsigned)f2bf(b) << 16);
}
static __device__ __forceinline__ float bf2lo(unsigned v){ return __uint_as_float(v << 16); }
static __device__ __forceinline__ float bf2hi(unsigned v){ return __uint_as_float(v & 0xffff0000u); }
static __device__ __forceinline__ float sigm_f(float x){ return 1.f / (1.f + __expf(-x)); }
static __device__ __forceinline__ float tanh_f(float x){
    float e = __expf(-2.f * fabsf(x));
    float t = (1.f - e) / (1.f + e);
    return copysignf(t, x);
}

// ---------------- prep: weights->bf16, zero state, mask decode ----------------
__global__ __launch_bounds__(256) void prep(
    const float* __restrict__ Wp, const float* __restrict__ Wih,
    const float* __restrict__ Whh, const float* __restrict__ bih,
    const float* __restrict__ bhh, const unsigned char* __restrict__ mraw,
    unsigned short* __restrict__ wp_bf, unsigned short* __restrict__ wz,
    float* __restrict__ bz, int* __restrict__ mski,
    unsigned* __restrict__ hg32, float* __restrict__ cst)
{
    __shared__ int mflagA, mflagB;
    const int bid = blockIdx.x, tid = threadIdx.x;
    const int i0 = bid * 256 + tid, stride = 512 * 256;
    for (int i = i0; i < 524288; i += stride)
        ((unsigned*)wp_bf)[i] = pack2(Wp[2*i], Wp[2*i + 1]);
    for (int i = i0; i < 81920; i += stride){
        int n = (2*i) / 320, k = (2*i) - n*320;
        float w0 = (k < 192)     ? Wih[n*192 + k]     : Whh[n*128 + k - 192];
        float w1 = (k + 1 < 192) ? Wih[n*192 + k + 1] : Whh[n*128 + k + 1 - 192];
        ((unsigned*)wz)[i] = pack2(w0, w1);
    }
    for (int i = i0; i < 512; i += stride) bz[i] = bih[i] + bhh[i];
    for (int i = i0; i < 32768; i += stride) hg32[i] = 0u;     // h(-1) = 0
    for (int i = i0; i < 65536; i += stride) cst[i] = 0.f;     // c(-1) = 0
    if (bid == 0){
        if (tid == 0){ mflagA = 0; mflagB = 0; }
        __syncthreads();
        for (int j = tid; j < 512; j += 256){
            unsigned char b = mraw[j];
            if (b && (j & 3))        atomicAdd(&mflagA, 1);
            if (b && ((j & 7) == 4)) atomicAdd(&mflagB, 1);
        }
        __syncthreads();
        for (int j = tid; j < 512; j += 256){
            int v;
            if (mflagA)      v = mraw[j] ? 1 : 0;
            else if (mflagB) v = ((const int*)mraw)[j] ? 1 : 0;
            else             v = ((const long long*)mraw)[j] ? 1 : 0;
            mski[j] = v;
        }
    }
}

// ---------------- KU: U-GEMM  U[j][c][:] = W_c . h(t-1)[j] --------------------
// block (mq 0..15, cp 0..31): rows mq*32..+32, cells {2cp, 2cp+1}
__global__ __launch_bounds__(256) void ku(
    const unsigned short* __restrict__ hg,
    const unsigned short* __restrict__ wp_bf,
    unsigned short* __restrict__ U)
{
    __shared__ unsigned short ustage[32][256];   // 16 KB
    const int bid = blockIdx.x, tid = threadIdx.x;
    const int mq = bid >> 5, cp = bid & 31;
    const int r0 = mq * 32;
    const int w = tid >> 6, lane = tid & 63;
    const int msub = w & 1, nq = w >> 1;
    const int lrow = lane & 15, lk = (lane >> 4) * 8;
    f32x4 acc[2][4] = {};
    #pragma unroll
    for (int ks = 0; ks < 4; ++ks){
        bf16x8 a = *(const bf16x8*)(hg + (r0 + msub*16 + lrow)*128 + ks*32 + lk);
        #pragma unroll
        for (int cell = 0; cell < 2; ++cell){
            #pragma unroll
            for (int ntl = 0; ntl < 4; ++ntl){
                const unsigned short* bp = wp_bf +
                    ((nq*4 + ntl)*16 + lrow)*8192 + (2*cp + cell)*128 + ks*32 + lk;
                acc[cell][ntl] = MFMA16(a, *(const bf16x8*)bp, acc[cell][ntl]);
            }
        }
    }
    const int crow = (lane >> 4) * 4, ccol = lane & 15;
    #pragma unroll
    for (int cell = 0; cell < 2; ++cell)
        #pragma unroll
        for (int ntl = 0; ntl < 4; ++ntl)
            #pragma unroll
            for (int r = 0; r < 4; ++r)
                ustage[msub*16 + crow + r][cell*128 + (nq*4 + ntl)*16 + ccol]
                    = f2bf(acc[cell][ntl][r]);
    __syncthreads();
    for (int e = tid; e < 1024; e += 256){
        int r = e >> 5, o = e & 31;
        *(ulonglong2*)((char*)U + ((long long)(r0 + r)*64 + 2*cp)*256 + o*16)
            = *(const ulonglong2*)&ustage[r][o*8];
    }
}

// ---------------- KGL: gather + soc/emb + LSTM + head (4 agents/block) --------
__global__ __launch_bounds__(512, 1) void kgl(
    const float* __restrict__ obs, const int* __restrict__ mski,
    const unsigned short* __restrict__ U, const unsigned short* __restrict__ wz,
    const float* __restrict__ bz, const float* __restrict__ b_p,
    const float* __restrict__ W_e, const float* __restrict__ b_e,
    const float* __restrict__ W_o, const float* __restrict__ b_o,
    const float* __restrict__ cur_rd, float* __restrict__ cur_wr,
    unsigned short* __restrict__ hg, float* __restrict__ cst,
    float* __restrict__ out, int t)
{
    __shared__ float2 pos[512];            // 4 KB
    __shared__ short  cellm[4][512];       // 4 KB
    __shared__ short  lst[4][512];         // 4 KB
    __shared__ int    nv[4];
    __shared__ float  socp[4][4][128];     // 8 KB
    __shared__ unsigned short x[16][328];  // 10.5 KB (rows 4-15 scratch for MFMA)
    __shared__ float  z[4][512];           // 8 KB
    __shared__ float  hf[4][128];          // 2 KB

    const int bid = blockIdx.x, tid = threadIdx.x;
    const int a0 = bid * 4;
    const int w = tid >> 6, lane = tid & 63;
    const int mode = (t < T_OBS) ? 0 : ((t == T_OBS) ? 1 : 2);

    // ---- positions (all 512 agents) ----
    {
        int j = tid;
        float px, py;
        if (mode == 2){
            float2 cv = ((const float2*)cur_rd)[j];
            px = cv.x; py = cv.y;
        } else {
            int tt = (mode == 0) ? t : (T_OBS - 1);
            px = obs[tt*1024 + 2*j]; py = obs[tt*1024 + 2*j + 1];
            if (isnan(px)) px = 0.f;
            if (isnan(py)) py = 0.f;
            if (mode == 1 && !mski[j]){ px = 0.f; py = 0.f; }
        }
        pos[j] = make_float2(px, py);
    }
    __syncthreads();

    // ---- cells: own 4 agents vs all j ----
    {
        int j = tid;
        float2 pj = pos[j];
        int mj = mski[j];
        #pragma unroll
        for (int a = 0; a < 4; ++a){
            int i = a0 + a;
            int cc = -1;
            if (mj && j != i && mski[i]){
                float rx = pj.x - pos[i].x, ry = pj.y - pos[i].y;
                if (fabsf(rx) < 32.f && fabsf(ry) < 32.f){
                    int col = (int)floorf((rx + 32.f) * 0.125f);
                    int row = (int)floorf((ry + 32.f) * 0.125f);
                    col = min(max(col, 0), 7); row = min(max(row, 0), 7);
                    cc = row*8 + col;
                }
            }
            cellm[a][j] = (short)cc;
        }
    }
    __syncthreads();

    // ---- ballot compaction: wave w (<4) -> agent w ----
    if (w < 4){
        int base = 0;
        for (int b = 0; b < 8; ++b){
            short cj = cellm[w][b*64 + lane];
            bool val = cj >= 0;
            unsigned long long bal = __ballot(val);
            int pre = __popcll(bal & ((1ull << lane) - 1ull));
            if (val) lst[w][base + pre] = (short)((b*64 + lane) | ((int)cj << 9));
            base += __popcll(bal);
        }
        if (lane == 0) nv[w] = base;
    }
    __syncthreads();

    // ---- gather U: agent al, 4 half-wave slots x unroll 16 -> 64 in flight ----
    {
        const int al = w & 3, sw = ((w >> 2) << 1) | (lane >> 5), lq = lane & 31;
        const int n = (t == 0) ? 0 : nv[al];
        const unsigned long long* ub = (const unsigned long long*)U;
        float s0 = 0.f, s1 = 0.f, s2 = 0.f, s3 = 0.f;
        int b4 = 0;
        for (; b4 + 64 <= n; b4 += 64){
            unsigned long long v[16];
            #pragma unroll
            for (int u = 0; u < 16; ++u){
                int pk = lst[al][b4 + u*4 + sw];
                v[u] = ub[(pk & 511)*2048 + (pk >> 9)*32 + lq];
            }
            #pragma unroll
            for (int u = 0; u < 16; ++u){
                unsigned lo = (unsigned)v[u], hi = (unsigned)(v[u] >> 32);
                s0 += bf2lo(lo); s1 += bf2hi(lo);
                s2 += bf2lo(hi); s3 += bf2hi(hi);
            }
        }
        // mid tail: 16-entry batches (4 slots x unroll 4)
        for (; b4 + 16 <= n; b4 += 16){
            unsigned long long v[4];
            #pragma unroll
            for (int u = 0; u < 4; ++u){
                int pk = lst[al][b4 + u*4 + sw];
                v[u] = ub[(pk & 511)*2048 + (pk >> 9)*32 + lq];
            }
            #pragma unroll
            for (int u = 0; u < 4; ++u){
                unsigned lo = (unsigned)v[u], hi = (unsigned)(v[u] >> 32);
                s0 += bf2lo(lo); s1 += bf2hi(lo);
                s2 += bf2lo(hi); s3 += bf2hi(hi);
            }
        }
        for (; b4 < n; b4 += 4){
            int e = b4 + sw;
            if (e < n){
                int pk = lst[al][e];
                unsigned long long v = ub[(pk & 511)*2048 + (pk >> 9)*32 + lq];
                unsigned lo = (unsigned)v, hi = (unsigned)(v >> 32);
                s0 += bf2lo(lo); s1 += bf2hi(lo); s2 += bf2lo(hi); s3 += bf2hi(hi);
            }
        }
        f32x4 sv = {s0, s1, s2, s3};
        *(f32x4*)&socp[al][sw][lq*4] = sv;
    }
    __syncthreads();

    // ---- x = [emb | soc | h(t-1)] for own 4 agents ----
    {
        int al = tid >> 7, u = tid & 127;
        float s = b_p[u] + socp[al][0][u] + socp[al][1][u]
                         + socp[al][2][u] + socp[al][3][u];
        if (!mski[a0 + al]) s = 0.f;
        x[al][64 + u] = f2bf(s);
    }
    if (tid < 256){
        int al = tid >> 6, u = tid & 63;
        float2 p = pos[a0 + al];
        float e = W_e[u*2]*p.x + W_e[u*2 + 1]*p.y + b_e[u];
        x[al][u] = f2bf(fmaxf(e, 0.f));
    }
    if (tid < 256){
        int al = tid >> 6, p2 = tid & 63;
        *(unsigned*)&x[al][192 + 2*p2] = ((const unsigned*)hg)[(a0 + al)*64 + p2];
    }
    __syncthreads();

    // ---- LSTM GEMM: z[4][512] = x[4][320] @ wz^T (wave w: cols w*64..+64) ----
    const int lrow = lane & 15, lk = (lane >> 4) * 8;
    {
        f32x4 zac[4] = {};
        #pragma unroll
        for (int ks = 0; ks < 10; ++ks){
            bf16x8 xa = *(const bf16x8*)&x[lrow][ks*32 + lk];
            #pragma unroll
            for (int nt = 0; nt < 4; ++nt)
                zac[nt] = MFMA16(xa,
                    *(const bf16x8*)(wz + (w*64 + nt*16 + lrow)*320 + ks*32 + lk),
                    zac[nt]);
        }
        if (lane < 16){   // crow==0 lanes hold C rows 0..3 = the 4 real agents
            #pragma unroll
            for (int nt = 0; nt < 4; ++nt)
                #pragma unroll
                for (int r = 0; r < 4; ++r)
                    z[r][w*64 + nt*16 + lane] = zac[nt][r];
        }
    }
    __syncthreads();

    // ---- gates -> c (global, block-owned), h -> hf ----
    {
        int al = tid >> 7, u = tid & 127;
        float zi = z[al][      u] + bz[      u];
        float zf = z[al][128 + u] + bz[128 + u];
        float zg = z[al][256 + u] + bz[256 + u];
        float zo = z[al][384 + u] + bz[384 + u];
        float ig = sigm_f(zi), fg = sigm_f(zf);
        float gv = tanh_f(zg), og = sigm_f(zo);
        int gi = (a0 + al)*128 + u;
        float cn = fg * cst[gi] + ig * gv;
        float hn = og * tanh_f(cn);
        cst[gi] = cn;
        hf[al][u] = hn;
    }
    __syncthreads();
    if (tid < 256){
        int al = tid >> 6, p2 = tid & 63;
        ((unsigned*)hg)[(a0 + al)*64 + p2] = pack2(hf[al][2*p2], hf[al][2*p2 + 1]);
    }

    // ---- decoder head: wave w (<4) -> agent w ----
    if (t >= T_OBS && w < 4){
        const int dec_t = t - T_OBS;
        const int ag = a0 + w;
        float h0 = hf[w][2*lane], h1 = hf[w][2*lane + 1];
        float p[5];
        #pragma unroll
        for (int o = 0; o < 5; ++o)
            p[o] = W_o[o*128 + 2*lane]*h0 + W_o[o*128 + 2*lane + 1]*h1;
        #pragma unroll
        for (int sh = 32; sh; sh >>= 1)
            #pragma unroll
            for (int o = 0; o < 5; ++o) p[o] += __shfl_xor(p[o], sh, 64);
        if (lane == 0){
            float mu0 = p[0] + b_o[0], mu1 = p[1] + b_o[1];
            float s0 = __expf(p[2] + b_o[2]) + 1e-6f;
            float s1 = __expf(p[3] + b_o[3]) + 1e-6f;
            float rh = tanh_f(p[4] + b_o[4]);
            float2 pi2 = pos[ag];        // = cur(t-1) (mode2) or masked obs[7] (mode1)
            float cx = pi2.x, cy = pi2.y;
            if (mski[ag]){ cx += mu0; cy += mu1; }
            cur_wr[ag*2] = cx; cur_wr[ag*2 + 1] = cy;
            out[dec_t*1024 + ag*2]             = cx;
            out[dec_t*1024 + ag*2 + 1]         = cy;
            out[12288 + dec_t*1024 + ag*2]     = s0;
            out[12288 + dec_t*1024 + ag*2 + 1] = s1;
            out[24576 + dec_t*512 + ag]        = rh;
        }
    }
}

extern "C" void kernel_launch(void* const* d_in, const int* in_sizes, int n_in,
                              void* d_out, int out_size, void* d_ws, size_t ws_size,
                              hipStream_t stream)
{
    const float* obs  = (const float*)d_in[0];
    const unsigned char* mraw = (const unsigned char*)d_in[1];
    const float* W_e  = (const float*)d_in[2];
    const float* b_e  = (const float*)d_in[3];
    const float* W_p  = (const float*)d_in[4];
    const float* b_p  = (const float*)d_in[5];
    const float* W_ih = (const float*)d_in[6];
    const float* W_hh = (const float*)d_in[7];
    const float* b_ih = (const float*)d_in[8];
    const float* b_hh = (const float*)d_in[9];
    const float* W_o  = (const float*)d_in[10];
    const float* b_o  = (const float*)d_in[11];
    float* out = (float*)d_out;

    char* ws = (char*)d_ws;
    unsigned short* wp_bf = (unsigned short*)(ws + WP_OFF);
    unsigned short* wz_bf = (unsigned short*)(ws + WZ_OFF);
    float* bz   = (float*)(ws + BZ_OFF);
    int*   mski = (int*)  (ws + MASK_OFF);
    float* cur[2] = { (float*)(ws + CUR0_OFF), (float*)(ws + CUR1_OFF) };
    unsigned short* hg = (unsigned short*)(ws + HG_OFF);
    float* cst  = (float*)(ws + CST_OFF);
    unsigned short* U  = (unsigned short*)(ws + U_OFF);

    prep<<<512, 256, 0, stream>>>(W_p, W_ih, W_hh, b_ih, b_hh, mraw,
                                  wp_bf, wz_bf, bz, mski, (unsigned*)hg, cst);

    for (int t = 0; t < T_OBS + PRED; ++t){
        if (t > 0)
            ku<<<512, 256, 0, stream>>>(hg, wp_bf, U);
        kgl<<<128, 512, 0, stream>>>(obs, mski, U, wz_bf, bz, b_p,
                                     W_e, b_e, W_o, b_o,
                                     cur[(t + 1) & 1], cur[t & 1],
                                     hg, cst, out, t);
    }
}